// Round 2
// baseline (196.614 us; speedup 1.0000x reference)
//
#include <hip/hip_runtime.h>
#include <math.h>

#define B_ 2
#define C_ 128
#define H_ 64
#define W_ 64
#define F_ 16
#define U_ 9
#define MD_ 4
#define UV_ 81
#define HW_ (H_*W_)
#define BF_ (B_*F_)

typedef float f32x4 __attribute__((ext_vector_type(4)));
typedef _Float16 f16x8 __attribute__((ext_vector_type(8)));

#define LDS_REF_STRIDE 65   // 64 px + 1 pad -> 2-way (free) bank pattern
#define LDS_TAR_STRIDE 73   // 72 cols (x=-4..67) + 1 pad -> 2-way (free)

// Scales (exact powers of two; leaky_relu commutes with positive scaling):
//   ref staged as 64*ref ; weights preloaded as 256*w ; store acc * 1/16384.
// Keeps fp16 hi/lo split residuals in the normal range -> ~2^-22 rel error
// per term, i.e. fp32-noise level (the bf16 split's 2^-17 caused argmax flips).
#define XSCALE   64.0f
#define WSCALE   256.0f
#define UNSCALE  (1.0f / 16384.0f)

// cvol layout in workspace: cvol[uv][bf][pix], bf = b*F_+f, uv = u*9+v
//   (u = x-shift index, v = y-shift index; displacement du=u-4, dv=v-4)
//
// MFMA formulation per (b, u, v, pixel-tile):
//   D[f][px] = sum_c W[f][c] * leaky(ref[c][px] * tar[c][px+du] (row y+dv))
// mfma_f32_16x16x32_f16, A = W (M=f=16), B = X = products (N=16 px), K = 32 c.
// W and X split hi/lo in fp16; 3 MFMAs give ~fp32-equivalent precision.
//
// Block = 256 thr = 4 waves = 4 pixel-tiles of one image row y.
// Grid = (y, v, b) = (64, 9, 2). Each block computes all 9 u for its v:
// one staged tar row (cols -4..67, halo always 0) serves all 9 u via px+u.
__global__ __launch_bounds__(256, 4)
void cvol_mfma_kernel(const float* __restrict__ ref,
                      const float* __restrict__ tar,
                      const float* __restrict__ pw,
                      float* __restrict__ cvol) {
    const int t    = threadIdx.x;
    const int lane = t & 63;
    const int wid  = t >> 6;           // wave id 0..3 = pixel tile
    const int ml   = lane & 15;        // A: f-row ; B: pixel within tile ; D: col
    const int grp  = lane >> 4;        // k-group (c offset grp*8) ; D: f = grp*4+r
    const int y    = blockIdx.x;       // image row
    const int v    = blockIdx.y;       // y-shift index 0..8
    const int b    = blockIdx.z;
    const int ys   = y + v - MD_;
    const int px   = wid * 16 + ml;    // pixel x 0..63

    // ---- OOB tar row: all 9 planes at this (y,v) are exactly zero ----
    if ((unsigned)ys >= (unsigned)H_) {
        #pragma unroll
        for (int i = 0; i < 36; ++i) {           // 9*16*64 = 9216 dwords
            int idx = i * 256 + t;
            int u   = idx >> 10;
            int f   = (idx >> 6) & 15;
            int xx  = idx & 63;
            cvol[((size_t)(u * U_ + v) * BF_ + b * F_ + f) * HW_ + y * W_ + xx] = 0.f;
        }
        return;
    }

    __shared__ float refS[32 * LDS_REF_STRIDE];
    __shared__ float tarS[32 * LDS_TAR_STRIDE];

    // halo columns (x<0, x>=W) are always out of range -> zero them once
    {
        int cr = t >> 3, h = t & 7;
        int col = (h < 4) ? h : (h + 64);        // cols 0..3 and 68..71
        tarS[cr * LDS_TAR_STRIDE + col] = 0.f;
    }

    // ---- preload weight A-fragments (x256) for all 4 K-chunks, hi/lo fp16 ----
    f16x8 whi[4], wlo[4];
    #pragma unroll
    for (int kc = 0; kc < 4; ++kc) {
        const float* wp = pw + ml * C_ + kc * 32 + grp * 8;
        #pragma unroll
        for (int j = 0; j < 8; ++j) {
            float wv = wp[j] * WSCALE;
            _Float16 h = (_Float16)wv;
            whi[kc][j] = h;
            wlo[kc][j] = (_Float16)(wv - (float)h);
        }
    }

    f32x4 acc[U_];
    #pragma unroll
    for (int u = 0; u < U_; ++u) acc[u] = f32x4{0.f, 0.f, 0.f, 0.f};

    const float* refB = ref + ((size_t)b * C_) * HW_ + y  * W_;
    const float* tarB = tar + ((size_t)b * C_) * HW_ + ys * W_;

    for (int kc = 0; kc < 4; ++kc) {
        const int c0 = kc * 32;
        __syncthreads();                          // LDS reuse from prev chunk
        // stage 32 c-rows: each wave writes 8 full rows (coalesced 256B loads)
        #pragma unroll
        for (int i = 0; i < 8; ++i) {
            int cr = i * 4 + wid;
            float rv = refB[(size_t)(c0 + cr) * HW_ + lane];
            float tv = tarB[(size_t)(c0 + cr) * HW_ + lane];
            refS[cr * LDS_REF_STRIDE + lane]     = rv * XSCALE;   // pre-scale x64
            tarS[cr * LDS_TAR_STRIDE + 4 + lane] = tv;
        }
        __syncthreads();

        float rv[8];
        #pragma unroll
        for (int j = 0; j < 8; ++j)
            rv[j] = refS[(grp * 8 + j) * LDS_REF_STRIDE + px];

        #pragma unroll
        for (int u = 0; u < U_; ++u) {
            f16x8 xhi, xlo;
            #pragma unroll
            for (int j = 0; j < 8; ++j) {
                float tv = tarS[(grp * 8 + j) * LDS_TAR_STRIDE + px + u];
                float p  = rv[j] * tv;            // scaled by 64
                p = fmaxf(p, 0.1f * p);           // leaky_relu(., 0.1)
                _Float16 h = (_Float16)p;
                xhi[j] = h;
                xlo[j] = (_Float16)(p - (float)h);
            }
            acc[u] = __builtin_amdgcn_mfma_f32_16x16x32_f16(whi[kc], xhi, acc[u], 0, 0, 0);
            acc[u] = __builtin_amdgcn_mfma_f32_16x16x32_f16(wlo[kc], xhi, acc[u], 0, 0, 0);
            acc[u] = __builtin_amdgcn_mfma_f32_16x16x32_f16(whi[kc], xlo, acc[u], 0, 0, 0);
        }
    }

    // ---- store: D row = f = grp*4+r, col = px ; 64B chunks per (f,tile) ----
    #pragma unroll
    for (int u = 0; u < U_; ++u) {
        float* op = cvol + ((size_t)(u * U_ + v) * BF_ + b * F_ + grp * 4) * HW_
                  + y * W_ + px;
        #pragma unroll
        for (int r = 0; r < 4; ++r)
            op[(size_t)r * HW_] = acc[u][r] * UNSCALE;
    }
}

// 4 threads per pixel, each owning a chunk of the 81 uv-planes.
// chunks (ascending uv): j=0 -> [0,21), j=1 -> [21,41), j=2 -> [41,61), j=3 -> [61,81)
__global__ __launch_bounds__(256)
void flowreg_kernel(const float* __restrict__ cvol,
                    float* __restrict__ out0) {
    const int lane = threadIdx.x & 63;
    const int j    = threadIdx.x >> 6;              // 0..3 = uv chunk = wave id
    const int blk  = blockIdx.x;                    // over BF_*HW_/64 = 2048
    const int bf   = blk >> 6;                      // 64 blocks per bf
    const int pix  = (blk & 63) * 64 + lane;

    const float* cp = cvol + (size_t)bf * HW_ + pix;
    const size_t stride = (size_t)BF_ * HW_;

    const int start = (j == 0) ? 0 : (1 + j * 20);
    const int n     = (j == 0) ? 21 : 20;

    float v[21];
#pragma unroll 21
    for (int i = 0; i < n; ++i) v[i] = cp[(size_t)(start + i) * stride];

    // local argmax (ascending, strict > keeps first occurrence)
    float mv = v[0]; int bi = start;
#pragma unroll 21
    for (int i = 1; i < n; ++i) {
        if (v[i] > mv) { mv = v[i]; bi = start + i; }
    }

    __shared__ float smax[4][64];
    __shared__ int   sidx[4][64];
    smax[j][lane] = mv; sidx[j][lane] = bi;
    __syncthreads();

    // combine chunks ascending -> global first-occurrence argmax (all threads)
    float m = smax[0][lane]; int best = sidx[0][lane];
#pragma unroll
    for (int k = 1; k < 4; ++k) {
        float vv = smax[k][lane];
        if (vv > m) { m = vv; best = sidx[k][lane]; }
    }
    int ub = best / U_;           // x-shift index of argmax
    int vb = best - ub * U_;      // y-shift index

    float S = 0.f, A = 0.f, Sx = 0.f, Sy = 0.f, gS = 0.f, gA = 0.f;
#pragma unroll 21
    for (int i = 0; i < n; ++i) {
        int uv = start + i;
        float d = v[i] - m;
        float z = __expf(d);
        gS += z; gA = fmaf(z, d, gA);
        int u = uv / U_, vy = uv - u * U_;
        int duc = u - ub, dvc = vy - vb;
        bool msk = (duc <= 3) && (duc >= -3) && (dvc <= 3) && (dvc >= -3);
        float zm = msk ? z : 0.f;
        float dm = msk ? d : 0.f;
        S += zm;
        A = fmaf(zm, dm, A);
        Sx = fmaf(zm, (float)(u - MD_), Sx);
        Sy = fmaf(zm, (float)(vy - MD_), Sy);
    }

    __shared__ float sred[6][4][64];
    sred[0][j][lane] = S;  sred[1][j][lane] = A;
    sred[2][j][lane] = Sx; sred[3][j][lane] = Sy;
    sred[4][j][lane] = gS; sred[5][j][lane] = gA;
    __syncthreads();

    if (j == 0) {
        float r[6];
#pragma unroll
        for (int q = 0; q < 6; ++q) {
            float s = sred[q][0][lane];
#pragma unroll
            for (int k = 1; k < 4; ++k) s += sred[q][k][lane];
            r[q] = s;
        }
        float invS = 1.f / r[0];
        float outx = r[2] * invS;
        float outy = r[3] * invS;
        // sum p*log p = A/S - log S  (p = z/S, log p = d - log S)
        float lent = (logf(r[0]) - r[1] * invS) * (1.0f / logf(49.0f));
        float gent = (logf(r[4]) - r[5] / r[4]) * (1.0f / logf(81.0f));

        float* op = out0 + (size_t)bf * 4 * HW_ + pix;
        op[0 * HW_] = outx;
        op[1 * HW_] = outy;
        op[2 * HW_] = lent;
        op[3 * HW_] = gent;
    }
}

__global__ __launch_bounds__(256)
void warp_kernel(const float* __restrict__ tar,
                 const float* __restrict__ out0,
                 float* __restrict__ warped) {
    int tid = blockIdx.x * 256 + threadIdx.x;   // over B_*C_*HW_
    int pix = tid & (HW_ - 1);
    int bc  = tid >> 12;
    int b   = bc >> 7;                          // C_ = 128
    int x = pix & 63, y = pix >> 6;

    // flow = hypothesis f=0 of out0 for this b
    const float* fbase = out0 + (size_t)(b * F_) * 4 * HW_;
    float fx = fbase[pix];
    float fy = fbase[HW_ + pix];
    float px = (float)x + fx;
    float py = (float)y + fy;

    bool inb = (fabsf(2.0f * px / (float)(W_ - 1) - 1.0f) < 1.0f) &&
               (fabsf(2.0f * py / (float)(H_ - 1) - 1.0f) < 1.0f);

    float x0 = floorf(px), y0 = floorf(py);
    float wx = px - x0,    wy = py - y0;
    int x0i = (int)x0, y0i = (int)y0;

    const float* img = tar + (size_t)bc * HW_;

    auto tap = [&](int yi, int xi, float wgt) -> float {
        bool v = ((unsigned)xi < (unsigned)W_) && ((unsigned)yi < (unsigned)H_);
        int xc = xi < 0 ? 0 : (xi > W_ - 1 ? W_ - 1 : xi);
        int yc = yi < 0 ? 0 : (yi > H_ - 1 ? H_ - 1 : yi);
        float val = img[yc * W_ + xc];
        return val * (v ? wgt : 0.f);
    };

    float acc = tap(y0i,     x0i,     (1.f - wx) * (1.f - wy))
              + tap(y0i,     x0i + 1, wx * (1.f - wy))
              + tap(y0i + 1, x0i,     (1.f - wx) * wy)
              + tap(y0i + 1, x0i + 1, wx * wy);

    warped[tid] = inb ? acc : 0.f;
}

extern "C" void kernel_launch(void* const* d_in, const int* in_sizes, int n_in,
                              void* d_out, int out_size, void* d_ws, size_t ws_size,
                              hipStream_t stream) {
    const float* ref = (const float*)d_in[0];
    const float* tar = (const float*)d_in[1];
    const float* pw  = (const float*)d_in[2];
    float* out0 = (float*)d_out;                       // (B*F, 4, H, W) = 524288 floats
    float* out1 = out0 + (size_t)BF_ * 4 * HW_;        // (B, C, H, W)  = 2097152 floats
    float* cvol = (float*)d_ws;                        // 81*32*4096 floats = 42.5 MB

    dim3 gc(H_, U_, B_);                               // (row, v, b)
    cvol_mfma_kernel<<<gc, 256, 0, stream>>>(ref, tar, pw, cvol);
    flowreg_kernel<<<(BF_ * HW_) / 64, 256, 0, stream>>>(cvol, out0);
    warp_kernel<<<(B_ * C_ * HW_) / 256, 256, 0, stream>>>(tar, out0, out1);
}

// Round 4
// 107.969 us; speedup vs baseline: 1.8210x; 1.8210x over previous
//
#include <hip/hip_runtime.h>
#include <math.h>

#define B_ 2
#define C_ 128
#define H_ 64
#define W_ 64
#define F_ 16
#define U_ 9
#define MD_ 4
#define UV_ 81
#define HW_ (H_*W_)
#define BF_ (B_*F_)

typedef float f32x4 __attribute__((ext_vector_type(4)));
typedef float f32x2 __attribute__((ext_vector_type(2)));
typedef _Float16 f16x2 __attribute__((ext_vector_type(2)));
typedef _Float16 f16x4 __attribute__((ext_vector_type(4)));
typedef _Float16 f16x8 __attribute__((ext_vector_type(8)));

#define RS 66   // refS row stride (dwords): even (8B-aligned b64 writes), 2-way-free reads
#define TS 74   // tarS row stride (dwords): ditto; cols 0..71 = x -4..67, 72/73 pad

// Scales (exact powers of two; leaky_relu commutes with positive scaling):
//   ref staged as 64*ref ; weights as 256*w ; store acc * 1/16384.
// fp16 hi/lo split -> ~2^-21 rel error per term = fp32-noise level (verified
// passing in round 2 with absmax 0.015625, identical to the fp32 kernel).
#define XSCALE   64.0f
#define WSCALE   256.0f
#define UNSCALE  (1.0f / 16384.0f)

static __device__ __forceinline__ f16x8 cat4(f16x2 a, f16x2 b, f16x2 c, f16x2 d) {
    f16x4 ab = __builtin_shufflevector(a, b, 0, 1, 2, 3);
    f16x4 cd = __builtin_shufflevector(c, d, 0, 1, 2, 3);
    return __builtin_shufflevector(ab, cd, 0, 1, 2, 3, 4, 5, 6, 7);
}

// exact hi/lo fp16 split of a packed f32 pair (1 pk_sub + 2 cvt + 2 cvt_pkrtz)
// NOTE: cvt_pkrtz returns an __fp16-based vector type -> bit_cast to f16x2.
static __device__ __forceinline__ void split2(f32x2 p, f16x2& hi, f16x2& lo) {
    hi = __builtin_bit_cast(f16x2, __builtin_amdgcn_cvt_pkrtz(p.x, p.y));
    f32x2 hf; hf.x = (float)hi.x; hf.y = (float)hi.y;
    f32x2 l = p - hf;                       // exact residual
    lo = __builtin_bit_cast(f16x2, __builtin_amdgcn_cvt_pkrtz(l.x, l.y));
}

// cvol layout in workspace: cvol[uv][bf][pix], bf = b*F_+f, uv = u*9+v
// D[f][px] = sum_c W[f][c] * leaky(ref[c,y,px] * tar[c,y+dv,px+du])
// mfma_f32_16x16x32_f16: A = W (lane: row=ml, k=grp*8+j), B = X (lane: k, col=ml),
// D: row f = grp*4+r, col = ml  — verified by the passing round-2 run.
__global__ __launch_bounds__(256, 4)
void cvol_mfma_kernel(const float* __restrict__ ref,
                      const float* __restrict__ tar,
                      const float* __restrict__ pw,
                      float* __restrict__ cvol) {
    const int t    = threadIdx.x;
    const int lane = t & 63;
    const int wid  = t >> 6;           // wave id = pixel tile
    const int ml   = lane & 15;
    const int grp  = lane >> 4;

    // Bijective XCD-chunk swizzle (grid 1152 = 8*144, XCD = blockIdx%8):
    // XCD k gets logical range [k*144,(k+1)*144) = one b, 16 consecutive y, all v
    // -> per-XCD working set ~1.3 MB << 4 MB L2.
    const int n   = blockIdx.x;
    const int L   = (n & 7) * 144 + (n >> 3);
    const int b   = L / 576;
    const int rem = L - b * 576;
    const int y   = rem / 9;
    const int v   = rem - y * 9;
    const int ys  = y + v - MD_;
    const int px  = wid * 16 + ml;

    // ---- OOB tar row: all 9 u-planes at this (y,v) are exactly zero ----
    if ((unsigned)ys >= (unsigned)H_) {
        const int f = t >> 4, c4 = (t & 15) * 4;
        f32x4 z = {0.f, 0.f, 0.f, 0.f};
        #pragma unroll
        for (int u = 0; u < U_; ++u)
            *(f32x4*)(cvol + ((size_t)(u * U_ + v) * BF_ + b * F_ + f) * HW_
                      + y * W_ + c4) = z;
        return;
    }

    __shared__ float lds[9216];              // 36 KB: staging  U  out-bounce
    float* refS = lds;                       // 32 x RS
    float* tarS = lds + 32 * RS;             // 32 x TS  (ends at 4480 < 9216)

    // halo columns (x<0, x>=W) always OOB -> zero once (never overwritten)
    {
        int cr = t >> 3, h = t & 7;
        int col = (h < 4) ? h : (h + 64);    // cols 0..3 and 68..71
        tarS[cr * TS + col] = 0.f;
    }

    const float* refB = ref + ((size_t)b * C_) * HW_ + y  * W_;
    const float* tarB = tar + ((size_t)b * C_) * HW_ + ys * W_;

    f32x4 acc[U_];
    #pragma unroll
    for (int u = 0; u < U_; ++u) acc[u] = f32x4{0.f, 0.f, 0.f, 0.f};

    // staging geometry: wave stages rows [wid*8, wid*8+8), dwordx4 per lane
    const int r0 = wid * 8 + grp;            // first row (q=0)
    const int c4 = 4 * ml;

    f32x4 nr0, nr1, nt0, nt1;                // prefetch registers (T14 split)
#define ISSUE(KC) {                                                              \
        nr0 = *(const f32x4*)(refB + (size_t)((KC)*32 + r0    ) * HW_ + c4);     \
        nr1 = *(const f32x4*)(refB + (size_t)((KC)*32 + r0 + 4) * HW_ + c4);     \
        nt0 = *(const f32x4*)(tarB + (size_t)((KC)*32 + r0    ) * HW_ + c4);     \
        nt1 = *(const f32x4*)(tarB + (size_t)((KC)*32 + r0 + 4) * HW_ + c4);     \
    }

    ISSUE(0);

    #pragma unroll
    for (int kc = 0; kc < 4; ++kc) {
        // weights for this kc (L1-hot after first block; issued early)
        f32x4 wa = *(const f32x4*)(pw + ml * C_ + kc * 32 + grp * 8);
        f32x4 wb = *(const f32x4*)(pw + ml * C_ + kc * 32 + grp * 8 + 4);

        __syncthreads();                     // LDS free from previous compute
        {   // write staged rows (ds_write_b64 pairs, 8B-aligned: RS/TS even)
            f32x2 a;
            a.x = nr0.x * XSCALE; a.y = nr0.y * XSCALE;
            *(f32x2*)(refS + (r0    ) * RS + c4    ) = a;
            a.x = nr0.z * XSCALE; a.y = nr0.w * XSCALE;
            *(f32x2*)(refS + (r0    ) * RS + c4 + 2) = a;
            a.x = nr1.x * XSCALE; a.y = nr1.y * XSCALE;
            *(f32x2*)(refS + (r0 + 4) * RS + c4    ) = a;
            a.x = nr1.z * XSCALE; a.y = nr1.w * XSCALE;
            *(f32x2*)(refS + (r0 + 4) * RS + c4 + 2) = a;
            a.x = nt0.x; a.y = nt0.y;
            *(f32x2*)(tarS + (r0    ) * TS + 4 + c4    ) = a;
            a.x = nt0.z; a.y = nt0.w;
            *(f32x2*)(tarS + (r0    ) * TS + 4 + c4 + 2) = a;
            a.x = nt1.x; a.y = nt1.y;
            *(f32x2*)(tarS + (r0 + 4) * TS + 4 + c4    ) = a;
            a.x = nt1.z; a.y = nt1.w;
            *(f32x2*)(tarS + (r0 + 4) * TS + 4 + c4 + 2) = a;
        }
        if (kc < 3) ISSUE(kc + 1);           // next tile in flight during compute
        __syncthreads();                     // staged tile ready

        // weight hi/lo split (scaled x256)
        f16x2 wh[4], wl[4];
        {
            f32x2 p;
            p.x = wa.x * WSCALE; p.y = wa.y * WSCALE; split2(p, wh[0], wl[0]);
            p.x = wa.z * WSCALE; p.y = wa.w * WSCALE; split2(p, wh[1], wl[1]);
            p.x = wb.x * WSCALE; p.y = wb.y * WSCALE; split2(p, wh[2], wl[2]);
            p.x = wb.z * WSCALE; p.y = wb.w * WSCALE; split2(p, wh[3], wl[3]);
        }
        f16x8 whi = cat4(wh[0], wh[1], wh[2], wh[3]);
        f16x8 wlo = cat4(wl[0], wl[1], wl[2], wl[3]);

        float rv[8];
        #pragma unroll
        for (int j = 0; j < 8; ++j)
            rv[j] = refS[(grp * 8 + j) * RS + px];      // already x64

        #pragma unroll
        for (int u = 0; u < U_; ++u) {
            f16x2 xh[4], xl[4];
            #pragma unroll
            for (int jp = 0; jp < 4; ++jp) {
                float t0 = tarS[(grp * 8 + 2 * jp    ) * TS + px + u];
                float t1 = tarS[(grp * 8 + 2 * jp + 1) * TS + px + u];
                f32x2 p;  p.x  = rv[2 * jp] * t0;  p.y  = rv[2 * jp + 1] * t1;
                f32x2 p1 = p * 0.1f;
                p = __builtin_elementwise_max(p, p1);   // leaky_relu, packed
                split2(p, xh[jp], xl[jp]);
            }
            f16x8 xhi = cat4(xh[0], xh[1], xh[2], xh[3]);
            f16x8 xlo = cat4(xl[0], xl[1], xl[2], xl[3]);
            acc[u] = __builtin_amdgcn_mfma_f32_16x16x32_f16(whi, xhi, acc[u], 0, 0, 0);
            acc[u] = __builtin_amdgcn_mfma_f32_16x16x32_f16(wlo, xhi, acc[u], 0, 0, 0);
            acc[u] = __builtin_amdgcn_mfma_f32_16x16x32_f16(whi, xlo, acc[u], 0, 0, 0);
        }
    }
#undef ISSUE

    // ---- full-line stores via LDS bounce: outS[u][f][px] ----
    __syncthreads();                         // staging reads done; reuse lds
    #pragma unroll
    for (int u = 0; u < U_; ++u) {
        #pragma unroll
        for (int r = 0; r < 4; ++r)
            lds[u * 1024 + (grp * 4 + r) * 64 + px] = acc[u][r] * UNSCALE;
    }
    __syncthreads();
    {
        const int f = t >> 4, c4o = (t & 15) * 4;
        #pragma unroll
        for (int u = 0; u < U_; ++u) {
            f32x4 val = *(const f32x4*)(lds + u * 1024 + t * 4);
            *(f32x4*)(cvol + ((size_t)(u * U_ + v) * BF_ + b * F_ + f) * HW_
                      + y * W_ + c4o) = val;             // 256B per 16-lane group
        }
    }
}

// 4 threads per pixel, each owning a chunk of the 81 uv-planes.
// chunks (ascending uv): j=0 -> [0,21), j=1 -> [21,41), j=2 -> [41,61), j=3 -> [61,81)
__global__ __launch_bounds__(256)
void flowreg_kernel(const float* __restrict__ cvol,
                    float* __restrict__ out0) {
    const int lane = threadIdx.x & 63;
    const int j    = threadIdx.x >> 6;              // 0..3 = uv chunk = wave id
    const int blk  = blockIdx.x;                    // over BF_*HW_/64 = 2048
    const int bf   = blk >> 6;                      // 64 blocks per bf
    const int pix  = (blk & 63) * 64 + lane;

    const float* cp = cvol + (size_t)bf * HW_ + pix;
    const size_t stride = (size_t)BF_ * HW_;

    const int start = (j == 0) ? 0 : (1 + j * 20);
    const int n     = (j == 0) ? 21 : 20;

    float v[21];
#pragma unroll 21
    for (int i = 0; i < n; ++i) v[i] = cp[(size_t)(start + i) * stride];

    // local argmax (ascending, strict > keeps first occurrence)
    float mv = v[0]; int bi = start;
#pragma unroll 21
    for (int i = 1; i < n; ++i) {
        if (v[i] > mv) { mv = v[i]; bi = start + i; }
    }

    __shared__ float smax[4][64];
    __shared__ int   sidx[4][64];
    smax[j][lane] = mv; sidx[j][lane] = bi;
    __syncthreads();

    // combine chunks ascending -> global first-occurrence argmax (all threads)
    float m = smax[0][lane]; int best = sidx[0][lane];
#pragma unroll
    for (int k = 1; k < 4; ++k) {
        float vv = smax[k][lane];
        if (vv > m) { m = vv; best = sidx[k][lane]; }
    }
    int ub = best / U_;           // x-shift index of argmax
    int vb = best - ub * U_;      // y-shift index

    float S = 0.f, A = 0.f, Sx = 0.f, Sy = 0.f, gS = 0.f, gA = 0.f;
#pragma unroll 21
    for (int i = 0; i < n; ++i) {
        int uv = start + i;
        float d = v[i] - m;
        float z = __expf(d);
        gS += z; gA = fmaf(z, d, gA);
        int u = uv / U_, vy = uv - u * U_;
        int duc = u - ub, dvc = vy - vb;
        bool msk = (duc <= 3) && (duc >= -3) && (dvc <= 3) && (dvc >= -3);
        float zm = msk ? z : 0.f;
        float dm = msk ? d : 0.f;
        S += zm;
        A = fmaf(zm, dm, A);
        Sx = fmaf(zm, (float)(u - MD_), Sx);
        Sy = fmaf(zm, (float)(vy - MD_), Sy);
    }

    __shared__ float sred[6][4][64];
    sred[0][j][lane] = S;  sred[1][j][lane] = A;
    sred[2][j][lane] = Sx; sred[3][j][lane] = Sy;
    sred[4][j][lane] = gS; sred[5][j][lane] = gA;
    __syncthreads();

    if (j == 0) {
        float r[6];
#pragma unroll
        for (int q = 0; q < 6; ++q) {
            float s = sred[q][0][lane];
#pragma unroll
            for (int k = 1; k < 4; ++k) s += sred[q][k][lane];
            r[q] = s;
        }
        float invS = 1.f / r[0];
        float outx = r[2] * invS;
        float outy = r[3] * invS;
        // sum p*log p = A/S - log S  (p = z/S, log p = d - log S)
        float lent = (logf(r[0]) - r[1] * invS) * (1.0f / logf(49.0f));
        float gent = (logf(r[4]) - r[5] / r[4]) * (1.0f / logf(81.0f));

        float* op = out0 + (size_t)bf * 4 * HW_ + pix;
        op[0 * HW_] = outx;
        op[1 * HW_] = outy;
        op[2 * HW_] = lent;
        op[3 * HW_] = gent;
    }
}

__global__ __launch_bounds__(256)
void warp_kernel(const float* __restrict__ tar,
                 const float* __restrict__ out0,
                 float* __restrict__ warped) {
    int tid = blockIdx.x * 256 + threadIdx.x;   // over B_*C_*HW_
    int pix = tid & (HW_ - 1);
    int bc  = tid >> 12;
    int b   = bc >> 7;                          // C_ = 128
    int x = pix & 63, y = pix >> 6;

    // flow = hypothesis f=0 of out0 for this b
    const float* fbase = out0 + (size_t)(b * F_) * 4 * HW_;
    float fx = fbase[pix];
    float fy = fbase[HW_ + pix];
    float px = (float)x + fx;
    float py = (float)y + fy;

    bool inb = (fabsf(2.0f * px / (float)(W_ - 1) - 1.0f) < 1.0f) &&
               (fabsf(2.0f * py / (float)(H_ - 1) - 1.0f) < 1.0f);

    float x0 = floorf(px), y0 = floorf(py);
    float wx = px - x0,    wy = py - y0;
    int x0i = (int)x0, y0i = (int)y0;

    const float* img = tar + (size_t)bc * HW_;

    auto tap = [&](int yi, int xi, float wgt) -> float {
        bool v = ((unsigned)xi < (unsigned)W_) && ((unsigned)yi < (unsigned)H_);
        int xc = xi < 0 ? 0 : (xi > W_ - 1 ? W_ - 1 : xi);
        int yc = yi < 0 ? 0 : (yi > H_ - 1 ? H_ - 1 : yi);
        float val = img[yc * W_ + xc];
        return val * (v ? wgt : 0.f);
    };

    float acc = tap(y0i,     x0i,     (1.f - wx) * (1.f - wy))
              + tap(y0i,     x0i + 1, wx * (1.f - wy))
              + tap(y0i + 1, x0i,     (1.f - wx) * wy)
              + tap(y0i + 1, x0i + 1, wx * wy);

    warped[tid] = inb ? acc : 0.f;
}

extern "C" void kernel_launch(void* const* d_in, const int* in_sizes, int n_in,
                              void* d_out, int out_size, void* d_ws, size_t ws_size,
                              hipStream_t stream) {
    const float* ref = (const float*)d_in[0];
    const float* tar = (const float*)d_in[1];
    const float* pw  = (const float*)d_in[2];
    float* out0 = (float*)d_out;                       // (B*F, 4, H, W) = 524288 floats
    float* out1 = out0 + (size_t)BF_ * 4 * HW_;        // (B, C, H, W)  = 2097152 floats
    float* cvol = (float*)d_ws;                        // 81*32*4096 floats = 42.5 MB

    cvol_mfma_kernel<<<1152, 256, 0, stream>>>(ref, tar, pw, cvol);
    flowreg_kernel<<<(BF_ * HW_) / 64, 256, 0, stream>>>(cvol, out0);
    warp_kernel<<<(B_ * C_ * HW_) / 256, 256, 0, stream>>>(tar, out0, out1);
}

// Round 5
// 105.064 us; speedup vs baseline: 1.8714x; 1.0277x over previous
//
#include <hip/hip_runtime.h>
#include <math.h>

#define B_ 2
#define C_ 128
#define H_ 64
#define W_ 64
#define F_ 16
#define U_ 9
#define MD_ 4
#define UV_ 81
#define HW_ (H_*W_)
#define BF_ (B_*F_)

typedef float f32x4 __attribute__((ext_vector_type(4)));
typedef float f32x2 __attribute__((ext_vector_type(2)));
typedef _Float16 f16x2 __attribute__((ext_vector_type(2)));
typedef _Float16 f16x4 __attribute__((ext_vector_type(4)));
typedef _Float16 f16x8 __attribute__((ext_vector_type(8)));

// Scales (exact powers of two; leaky_relu commutes with positive scaling).
// fp16 hi/lo split -> ~2^-21 rel error per term (verified passing r2/r4).
#define XSCALE   64.0f
#define WSCALE   256.0f
#define UNSCALE  (1.0f / 16384.0f)

// LDS map (floats). Staging phase: tar tile [0,12096) as [c*9+r][42]
// (c = channel within 32-chunk, r = tar row index = v, cols = x0-4..x0+35),
// ref tile [12096,13120) as [c][32]. Epilogue reuses [0,...) for
// pvol[4f][81 uv][34] (=11016) + scratch below.
#define TARS 42
#define REFO 12096
#define SM_  11016
#define SI_  11528
#define SU_  12040
#define LDSZ 15112

static __device__ __forceinline__ f16x8 cat4(f16x2 a, f16x2 b, f16x2 c, f16x2 d) {
    f16x4 ab = __builtin_shufflevector(a, b, 0, 1, 2, 3);
    f16x4 cd = __builtin_shufflevector(c, d, 0, 1, 2, 3);
    return __builtin_shufflevector(ab, cd, 0, 1, 2, 3, 4, 5, 6, 7);
}

// exact hi/lo fp16 split of a packed f32 pair
static __device__ __forceinline__ void split2(f32x2 p, f16x2& hi, f16x2& lo) {
    hi = __builtin_bit_cast(f16x2, __builtin_amdgcn_cvt_pkrtz(p.x, p.y));
    f32x2 hf; hf.x = (float)hi.x; hf.y = (float)hi.y;
    f32x2 l = p - hf;
    lo = __builtin_bit_cast(f16x2, __builtin_amdgcn_cvt_pkrtz(l.x, l.y));
}

// Fused cost-volume + flow_reg. Block = 512 thr = 8 waves = (xt 0..1) x (uvg 0..3).
// Block owns (b, y, x-half): computes cvol[f][uv][px] for 32 px in registers
// (MFMA, A = weights, B = leaky(ref*tar'), verified fragment mapping from r2/r4),
// then runs flow_reg per f in an LDS epilogue. No workspace use at all.
__global__ __launch_bounds__(512, 2)
void fused_kernel(const float* __restrict__ ref,
                  const float* __restrict__ tar,
                  const float* __restrict__ pw,
                  float* __restrict__ out0) {
    const int t    = threadIdx.x;
    const int lane = t & 63;
    const int wid  = t >> 6;
    const int xt   = wid & 1;
    const int uvg  = wid >> 1;
    const int ml   = lane & 15;
    const int grp  = lane >> 4;
    const int pxl  = xt * 16 + ml;          // pixel within 32-px block

    // XCD-chunked bijective decode: grid 256 = 8 XCD x 32 contiguous (b,y,xh)
    const int n0 = blockIdx.x;
    const int L  = (n0 & 7) * 32 + (n0 >> 3);
    const int b  = L >> 7;
    const int y  = (L >> 1) & 63;
    const int xh = L & 1;
    const int x0 = xh * 32;

    const int start = (uvg == 0) ? 0 : (1 + uvg * 20);

    __shared__ float lds[LDSZ];

    const float* refB = ref + ((size_t)b * C_) * HW_ + y * W_ + x0;
    const float* tarB = tar + ((size_t)b * C_) * HW_;

    // uv decode for this wave's chunk (static-indexed register arrays)
    int uA[21], vA[21];
    #pragma unroll
    for (int i = 0; i < 21; ++i) {
        int uv = start + i;
        int uu = uv / 9;
        uA[i] = uu; vA[i] = uv - uu * 9;
    }

    float nstg[23], nref[2];

    // stage-issue: 288 segments (c 0..31, r 0..8) x 40 cols, flat over 512 thr.
    // OOB rows/cols -> 0 (zero-padded correlation, matches reference).
#define SISSUE(KC) {                                                          \
    _Pragma("unroll")                                                         \
    for (int it = 0; it < 23; ++it) {                                         \
        int idx = it * 512 + t;                                               \
        int seg = idx / 40;                                                   \
        int col = idx - seg * 40;                                             \
        int c   = seg / 9;                                                    \
        int r   = seg - c * 9;                                                \
        int cc  = c > 31 ? 31 : c;                                            \
        int ysr = y + r - 4;                                                  \
        int xg  = x0 - 4 + col;                                               \
        bool ok = (it < 22 || t < 256) &&                                     \
                  ((unsigned)ysr < 64u) && ((unsigned)xg < 64u);              \
        int ysc = ysr < 0 ? 0 : (ysr > 63 ? 63 : ysr);                        \
        int xgc = xg  < 0 ? 0 : (xg  > 63 ? 63 : xg);                         \
        float vL = tarB[(size_t)((KC) * 32 + cc) * HW_ + ysc * W_ + xgc];     \
        nstg[it] = ok ? vL : 0.f;                                             \
    }                                                                         \
    _Pragma("unroll")                                                         \
    for (int it = 0; it < 2; ++it) {                                          \
        int idx = it * 512 + t;                                               \
        nref[it] = refB[(size_t)((KC) * 32 + (idx >> 5)) * HW_ + (idx & 31)]; \
    } }

#define SWRITE() {                                                            \
    _Pragma("unroll")                                                         \
    for (int it = 0; it < 23; ++it) {                                         \
        int idx = it * 512 + t;                                               \
        if (it < 22 || t < 256) {                                             \
            int seg = idx / 40;                                               \
            int col = idx - seg * 40;                                         \
            lds[seg * TARS + col] = nstg[it];                                 \
        }                                                                     \
    }                                                                         \
    _Pragma("unroll")                                                         \
    for (int it = 0; it < 2; ++it) {                                          \
        int idx = it * 512 + t;                                               \
        lds[REFO + idx] = nref[it] * XSCALE;                                  \
    } }

    f32x4 acc[21];
    #pragma unroll
    for (int i = 0; i < 21; ++i) acc[i] = f32x4{0.f, 0.f, 0.f, 0.f};

    SISSUE(0);

    for (int kc = 0; kc < 4; ++kc) {
        f32x4 wa = *(const f32x4*)(pw + ml * C_ + kc * 32 + grp * 8);
        f32x4 wb = *(const f32x4*)(pw + ml * C_ + kc * 32 + grp * 8 + 4);

        __syncthreads();                 // previous chunk's readers done
        SWRITE();
        if (kc < 3) SISSUE(kc + 1);      // next chunk in flight during compute
        __syncthreads();                 // staged tile ready

        f16x2 wh[4], wl[4];
        {
            f32x2 p;
            p.x = wa.x * WSCALE; p.y = wa.y * WSCALE; split2(p, wh[0], wl[0]);
            p.x = wa.z * WSCALE; p.y = wa.w * WSCALE; split2(p, wh[1], wl[1]);
            p.x = wb.x * WSCALE; p.y = wb.y * WSCALE; split2(p, wh[2], wl[2]);
            p.x = wb.z * WSCALE; p.y = wb.w * WSCALE; split2(p, wh[3], wl[3]);
        }
        f16x8 whi = cat4(wh[0], wh[1], wh[2], wh[3]);
        f16x8 wlo = cat4(wl[0], wl[1], wl[2], wl[3]);

        float rv[8];
        #pragma unroll
        for (int j = 0; j < 8; ++j)
            rv[j] = lds[REFO + (grp * 8 + j) * 32 + pxl];   // already x64

        const int rowbase = grp * 8 * (9 * TARS);

#define UVBODY(i) {                                                           \
        const int cb = vA[i] * TARS + pxl + uA[i];                            \
        f16x2 xh4[4], xl4[4];                                                 \
        _Pragma("unroll")                                                     \
        for (int jp = 0; jp < 4; ++jp) {                                      \
            float t0 = lds[rowbase + (2 * jp    ) * (9 * TARS) + cb];         \
            float t1 = lds[rowbase + (2 * jp + 1) * (9 * TARS) + cb];         \
            f32x2 p;  p.x = rv[2 * jp] * t0;  p.y = rv[2 * jp + 1] * t1;      \
            f32x2 p1 = p * 0.1f;                                              \
            p = __builtin_elementwise_max(p, p1);                             \
            split2(p, xh4[jp], xl4[jp]);                                      \
        }                                                                     \
        f16x8 xhi = cat4(xh4[0], xh4[1], xh4[2], xh4[3]);                     \
        f16x8 xlo = cat4(xl4[0], xl4[1], xl4[2], xl4[3]);                     \
        acc[i] = __builtin_amdgcn_mfma_f32_16x16x32_f16(whi, xhi, acc[i], 0, 0, 0); \
        acc[i] = __builtin_amdgcn_mfma_f32_16x16x32_f16(wlo, xhi, acc[i], 0, 0, 0); \
        acc[i] = __builtin_amdgcn_mfma_f32_16x16x32_f16(whi, xlo, acc[i], 0, 0, 0); }

        #pragma unroll
        for (int i = 0; i < 20; ++i) UVBODY(i);
        if (uvg == 0) UVBODY(20);
    }
    __syncthreads();                     // staging dead; epilogue reuses LDS

    // ---- epilogue: 4 passes of 4 f-planes; flow_reg per (f, px) ----
    const int jw  = t >> 7;
    const int rem = t & 127;
    const int fl  = rem >> 5;
    const int px  = rem & 31;

#define PH1(S0, N) {                                                          \
    _Pragma("unroll")                                                         \
    for (int i = 0; i < (N); ++i)                                             \
        vv[i] = lds[(fl * 81 + (S0) + i) * 34 + px];                          \
    mv = vv[0]; bi = (S0);                                                    \
    _Pragma("unroll")                                                         \
    for (int i = 1; i < (N); ++i)                                             \
        if (vv[i] > mv) { mv = vv[i]; bi = (S0) + i; } }

#define PH2(S0, N) {                                                          \
    _Pragma("unroll")                                                         \
    for (int i = 0; i < (N); ++i) {                                           \
        const int uvx = (S0) + i;                                             \
        const int uu = uvx / 9, vy = uvx - 9 * (uvx / 9);                     \
        float d = vv[i] - m; float z = __expf(d);                             \
        gS += z; gA = fmaf(z, d, gA);                                         \
        int duc = uu - ub, dvc = vy - vb;                                     \
        bool msk = (duc <= 3) && (duc >= -3) && (dvc <= 3) && (dvc >= -3);    \
        float zm = msk ? z : 0.f, dm = msk ? d : 0.f;                         \
        S += zm; A = fmaf(zm, dm, A);                                         \
        Sx = fmaf(zm, (float)(uu - MD_), Sx);                                 \
        Sy = fmaf(zm, (float)(vy - MD_), Sy); } }

    for (int P = 0; P < 4; ++P) {
        // bounce this wave's uv-chunk for f = 4P..4P+3 (lanes grp==P hold them)
#define BOUNCE(i) {                                                           \
        int uvx = start + (i);                                                \
        if (grp == P) {                                                       \
            lds[(0 * 81 + uvx) * 34 + pxl] = acc[i][0] * UNSCALE;             \
            lds[(1 * 81 + uvx) * 34 + pxl] = acc[i][1] * UNSCALE;             \
            lds[(2 * 81 + uvx) * 34 + pxl] = acc[i][2] * UNSCALE;             \
            lds[(3 * 81 + uvx) * 34 + pxl] = acc[i][3] * UNSCALE; } }
        #pragma unroll
        for (int i = 0; i < 20; ++i) BOUNCE(i);
        if (uvg == 0) BOUNCE(20);
        __syncthreads();

        float vv[21]; float mv; int bi;
        if      (jw == 0) { PH1(0, 21) }
        else if (jw == 1) { PH1(21, 20) }
        else if (jw == 2) { PH1(41, 20) }
        else              { PH1(61, 20) }
        lds[SM_ + t] = mv; lds[SI_ + t] = (float)bi;
        __syncthreads();

        // ascending 4-chunk combine -> global first-occurrence argmax
        float m = lds[SM_ + rem]; int best = (int)lds[SI_ + rem];
        #pragma unroll
        for (int k = 1; k < 4; ++k) {
            float mk = lds[SM_ + rem + 128 * k];
            if (mk > m) { m = mk; best = (int)lds[SI_ + rem + 128 * k]; }
        }
        int ub = best / 9, vb = best - 9 * (best / 9);

        float S = 0.f, A = 0.f, Sx = 0.f, Sy = 0.f, gS = 0.f, gA = 0.f;
        if      (jw == 0) { PH2(0, 21) }
        else if (jw == 1) { PH2(21, 20) }
        else if (jw == 2) { PH2(41, 20) }
        else              { PH2(61, 20) }
        lds[SU_ + 0 * 512 + t] = S;  lds[SU_ + 1 * 512 + t] = A;
        lds[SU_ + 2 * 512 + t] = Sx; lds[SU_ + 3 * 512 + t] = Sy;
        lds[SU_ + 4 * 512 + t] = gS; lds[SU_ + 5 * 512 + t] = gA;
        __syncthreads();

        if (t < 128) {
            float rq[6];
            #pragma unroll
            for (int q = 0; q < 6; ++q) {
                float s = lds[SU_ + q * 512 + t];
                #pragma unroll
                for (int k = 1; k < 4; ++k) s += lds[SU_ + q * 512 + t + 128 * k];
                rq[q] = s;
            }
            float invS = 1.f / rq[0];
            float outx = rq[2] * invS;
            float outy = rq[3] * invS;
            float lent = (logf(rq[0]) - rq[1] * invS) * (1.0f / logf(49.0f));
            float gent = (logf(rq[4]) - rq[5] / rq[4]) * (1.0f / logf(81.0f));
            float* op = out0 + ((size_t)(b * F_ + P * 4 + fl) * 4) * HW_
                      + y * W_ + x0 + px;
            op[0 * HW_] = outx;
            op[1 * HW_] = outy;
            op[2 * HW_] = lent;
            op[3 * HW_] = gent;
        }
        __syncthreads();                 // protect pvol/scratch for next pass
    }
}

__global__ __launch_bounds__(256)
void warp_kernel(const float* __restrict__ tar,
                 const float* __restrict__ out0,
                 float* __restrict__ warped) {
    int tid = blockIdx.x * 256 + threadIdx.x;   // over B_*C_*HW_
    int pix = tid & (HW_ - 1);
    int bc  = tid >> 12;
    int b   = bc >> 7;                          // C_ = 128
    int x = pix & 63, y = pix >> 6;

    // flow = hypothesis f=0 of out0 for this b
    const float* fbase = out0 + (size_t)(b * F_) * 4 * HW_;
    float fx = fbase[pix];
    float fy = fbase[HW_ + pix];
    float px = (float)x + fx;
    float py = (float)y + fy;

    bool inb = (fabsf(2.0f * px / (float)(W_ - 1) - 1.0f) < 1.0f) &&
               (fabsf(2.0f * py / (float)(H_ - 1) - 1.0f) < 1.0f);

    float x0 = floorf(px), y0 = floorf(py);
    float wx = px - x0,    wy = py - y0;
    int x0i = (int)x0, y0i = (int)y0;

    const float* img = tar + (size_t)bc * HW_;

    auto tap = [&](int yi, int xi, float wgt) -> float {
        bool v = ((unsigned)xi < (unsigned)W_) && ((unsigned)yi < (unsigned)H_);
        int xc = xi < 0 ? 0 : (xi > W_ - 1 ? W_ - 1 : xi);
        int yc = yi < 0 ? 0 : (yi > H_ - 1 ? H_ - 1 : yi);
        float val = img[yc * W_ + xc];
        return val * (v ? wgt : 0.f);
    };

    float acc = tap(y0i,     x0i,     (1.f - wx) * (1.f - wy))
              + tap(y0i,     x0i + 1, wx * (1.f - wy))
              + tap(y0i + 1, x0i,     (1.f - wx) * wy)
              + tap(y0i + 1, x0i + 1, wx * wy);

    warped[tid] = inb ? acc : 0.f;
}

extern "C" void kernel_launch(void* const* d_in, const int* in_sizes, int n_in,
                              void* d_out, int out_size, void* d_ws, size_t ws_size,
                              hipStream_t stream) {
    const float* ref = (const float*)d_in[0];
    const float* tar = (const float*)d_in[1];
    const float* pw  = (const float*)d_in[2];
    float* out0 = (float*)d_out;                       // (B*F, 4, H, W)
    float* out1 = out0 + (size_t)BF_ * 4 * HW_;        // (B, C, H, W)
    (void)d_ws; (void)ws_size;                         // workspace unused

    fused_kernel<<<256, 512, 0, stream>>>(ref, tar, pw, out0);
    warp_kernel<<<(B_ * C_ * HW_) / 256, 256, 0, stream>>>(tar, out0, out1);
}